// Round 7
// baseline (173.652 us; speedup 1.0000x reference)
//
#include <hip/hip_runtime.h>
#include <math.h>

#define Nq 2048
#define Bq 8
#define Kq 4
#define BKq 32
#define NE 16  // elements per lane (2048 / (2 waves * 64 lanes))
#define TWO_PI_D 6.283185307179586
#define PI_D 3.141592653589793
#define INV2PI_D 0.15915494309189535

// ---------------- wave helpers ----------------

__device__ __forceinline__ double wave_sum_d(double v) {
#pragma unroll
  for (int off = 1; off < 64; off <<= 1) v += __shfl_xor(v, off, 64);
  return v;
}

// Canonical GCN DPP wave64 sum; result uniform via readlane 63.
__device__ __forceinline__ float dpp_sum_f32(float v) {
  v += __int_as_float(__builtin_amdgcn_update_dpp(0, __float_as_int(v), 0x111, 0xf, 0xf, false));
  v += __int_as_float(__builtin_amdgcn_update_dpp(0, __float_as_int(v), 0x112, 0xf, 0xf, false));
  v += __int_as_float(__builtin_amdgcn_update_dpp(0, __float_as_int(v), 0x114, 0xf, 0xe, false));
  v += __int_as_float(__builtin_amdgcn_update_dpp(0, __float_as_int(v), 0x118, 0xf, 0xc, false));
  v += __int_as_float(__builtin_amdgcn_update_dpp(0, __float_as_int(v), 0x142, 0xa, 0xf, false));
  v += __int_as_float(__builtin_amdgcn_update_dpp(0, __float_as_int(v), 0x143, 0xc, 0xf, false));
  return __int_as_float(__builtin_amdgcn_readlane(__float_as_int(v), 63));
}

__device__ __forceinline__ float dpp_up1(float v) {  // lane i <- lane i-1
  return __int_as_float(__builtin_amdgcn_update_dpp(0, __float_as_int(v), 0x138, 0xf, 0xf, false));
}
__device__ __forceinline__ float dpp_dn1(float v) {  // lane i <- lane i+1
  return __int_as_float(__builtin_amdgcn_update_dpp(0, __float_as_int(v), 0x130, 0xf, 0xf, false));
}

__device__ __forceinline__ double lane_excl_prefix_d(double T, int lane) {
  double acc = T;
#pragma unroll
  for (int off = 1; off < 64; off <<= 1) {
    double t = __shfl_up(acc, off, 64);
    if (lane >= off) acc += t;
  }
  return acc - T;
}

__device__ __forceinline__ void fast_sincos_ph(double ph, float* sn, float* cs) {
  double k = trunc(ph * INV2PI_D);
  float phr = (float)(ph - k * TWO_PI_D);
  __sincosf(phr, sn, cs);
}

// Ap = (coef*opedoub + diag) p over this wave's 1024-row segment (16/lane).
// hL*/hR* are the neighbor-wave p values at the pair boundary.
template <bool UNIT>
__device__ __forceinline__ void applyA16(const float* p, float* Ap,
                                         const float* dd, float c, float c3,
                                         float c4, float ddu, float hL0,
                                         float hL1, float hR0, float hR1,
                                         int lane, int half) {
  float lm1 = dpp_up1(p[NE - 1]);
  float lm2 = dpp_up1(p[NE - 2]);
  float rp1 = dpp_dn1(p[0]);
  float rp2 = dpp_dn1(p[1]);
  if (lane == 0) { lm1 = hL1; lm2 = hL0; }    // rows i-1, i-2 from left wave
  if (lane == 63) { rp1 = hR0; rp2 = hR1; }   // rows i+1, i+2 from right wave
#pragma unroll
  for (int e = 0; e < NE; ++e) {
    float m2 = (e >= 2) ? p[e - 2] : (e == 1 ? lm1 : lm2);
    float m1 = (e >= 1) ? p[e - 1] : lm1;
    float q1 = (e <= NE - 2) ? p[e + 1] : rp1;
    float q2 = (e <= NE - 3) ? p[e + 2] : (e == NE - 2 ? rp1 : rp2);
    float u = fmaf(c, m2 + q2, -(c4 * (m1 + q1)));
    Ap[e] = fmaf(UNIT ? ddu : dd[e], p[e], u);
  }
  if (half == 0 && lane == 0) {  // global rows 0,1
    float d0 = (UNIT ? ddu : dd[0]) - c4;
    Ap[0] = fmaf(d0, p[0], fmaf(c, p[2], -(c3 * p[1])));
    float d1 = UNIT ? ddu : dd[1];
    Ap[1] = fmaf(d1, p[1], -(c3 * p[0])) + fmaf(c, p[3], -(c4 * p[2]));
  }
  if (half == 1 && lane == 63) {  // global rows N-2, N-1
    float dm2 = UNIT ? ddu : dd[NE - 2];
    Ap[NE - 2] = fmaf(dm2, p[NE - 2], c * p[NE - 4]) -
                 fmaf(c4, p[NE - 3], c3 * p[NE - 1]);
    float dm1 = (UNIT ? ddu : dd[NE - 1]) - c4;
    Ap[NE - 1] = fmaf(dm1, p[NE - 1], c * p[NE - 3]) - c3 * p[NE - 2];
  }
}

// 2-wave CG, single reduction point per iteration (3 partials; rsnew via the
// exact identity ||r - a Ap||^2 = rs - 2a r.Ap + a^2 ||Ap||^2).
// hx* = x0 boundary halos. Freeze-on-done == reference semantics.
template <bool UNIT>
__device__ __forceinline__ void cg_wave2(float coef, float* dd, float* r,
                                         float* x, float hxL0, float hxL1,
                                         float hxR0, float hxR1, int lane,
                                         int half, int wv,
                                         float (*sh_part)[4],
                                         float (*sh_rb)[2]) {
  const float c = coef, c3 = 3.0f * coef, c4 = 4.0f * coef;
  const float ddu = 6.0f * coef + (1.0f + 1e-6f);
  if (!UNIT) {
#pragma unroll
    for (int e = 0; e < NE; ++e) dd[e] += 6.0f * coef;
  }
  const int nb = wv ^ 1;
  float p[NE], Ap[NE];
  applyA16<UNIT>(x, Ap, dd, c, c3, c4, ddu, hxL0, hxL1, hxR0, hxR1, lane, half);
  float s0 = 0.f, s1 = 0.f;
#pragma unroll
  for (int e = 0; e < NE; ++e) {
    r[e] -= Ap[e];
    p[e] = r[e];
    ((e & 1) ? s1 : s0) = fmaf(r[e], r[e], (e & 1) ? s1 : s0);
  }
  float rsp = dpp_sum_f32(s0 + s1);
  if (lane == 0) sh_part[wv][3] = rsp;
  if (half == 0) {
    if (lane == 63) { sh_rb[wv][0] = r[NE - 2]; sh_rb[wv][1] = r[NE - 1]; }
  } else {
    if (lane == 0) { sh_rb[wv][0] = r[0]; sh_rb[wv][1] = r[1]; }
  }
  __syncthreads();
  float rs = rsp + sh_part[nb][3];
  float hL0 = 0.f, hL1 = 0.f, hR0 = 0.f, hR1 = 0.f;  // p halos (p = r init)
  if (half == 1) { hL0 = sh_rb[nb][0]; hL1 = sh_rb[nb][1]; }
  else { hR0 = sh_rb[nb][0]; hR1 = sh_rb[nb][1]; }
  bool done = false;
  for (int it = 0; it < 30; ++it) {
    applyA16<UNIT>(p, Ap, dd, c, c3, c4, ddu, hL0, hL1, hR0, hR1, lane, half);
    float pa0 = 0.f, pa1 = 0.f, aa0 = 0.f, aa1 = 0.f, ra0 = 0.f, ra1 = 0.f;
#pragma unroll
    for (int e = 0; e < NE; ++e) {
      if (e & 1) {
        pa1 = fmaf(p[e], Ap[e], pa1);
        aa1 = fmaf(Ap[e], Ap[e], aa1);
        ra1 = fmaf(r[e], Ap[e], ra1);
      } else {
        pa0 = fmaf(p[e], Ap[e], pa0);
        aa0 = fmaf(Ap[e], Ap[e], aa0);
        ra0 = fmaf(r[e], Ap[e], ra0);
      }
    }
    float papp = dpp_sum_f32(pa0 + pa1);
    float aapp = dpp_sum_f32(aa0 + aa1);
    float rapp = dpp_sum_f32(ra0 + ra1);
    if (lane == 0) {
      sh_part[wv][0] = papp;
      sh_part[wv][1] = aapp;
      sh_part[wv][2] = rapp;
    }
    __syncthreads();  // B1: partials visible (both waves add same two floats)
    float pap = papp + sh_part[nb][0];
    float apap = aapp + sh_part[nb][1];
    float rap = rapp + sh_part[nb][2];
    float a = __fdividef(rs, pap + 1e-12f);
    float rsnew = fmaf(a * a, apap, fmaf(-2.0f * a, rap, rs));
    if (!done) {
#pragma unroll
      for (int e = 0; e < NE; ++e) {
        x[e] = fmaf(a, p[e], x[e]);
        r[e] = fmaf(-a, Ap[e], r[e]);
      }
    }
    bool done1 = done || (rsnew < 1e-12f);  // == sqrt(rsnew) < 1e-6
    float bta = __fdividef(rsnew, rs + 1e-12f);
    if (!done1) {
#pragma unroll
      for (int e = 0; e < NE; ++e) p[e] = fmaf(bta, p[e], r[e]);
      rs = rsnew;
      if (half == 0) {
        if (lane == 63) { sh_rb[wv][0] = r[NE - 2]; sh_rb[wv][1] = r[NE - 1]; }
      } else {
        if (lane == 0) { sh_rb[wv][0] = r[0]; sh_rb[wv][1] = r[1]; }
      }
    }
    __syncthreads();  // B2: boundary r visible
    if (!done1) {
      // reconstruct neighbor's new boundary p = fmaf(beta, p_old, r) bit-exact
      if (half == 1) {
        hL0 = fmaf(bta, hL0, sh_rb[nb][0]);
        hL1 = fmaf(bta, hL1, sh_rb[nb][1]);
      } else {
        hR0 = fmaf(bta, hR0, sh_rb[nb][0]);
        hR1 = fmaf(bta, hR1, sh_rb[nb][1]);
      }
    }
    done = done1;
  }
}

__device__ __forceinline__ double blk_reduce(double v, double* sh) {
#pragma unroll
  for (int off = 32; off > 0; off >>= 1) v += __shfl_down(v, off, 64);
  int wid = threadIdx.x >> 6;
  int lane = threadIdx.x & 63;
  __syncthreads();
  if (lane == 0) sh[wid] = v;
  __syncthreads();
  double r = sh[0] + sh[1] + sh[2] + sh[3];
  __syncthreads();
  return r;
}

// ---- mega kernel: 1 block/row, 4 waves: {0,1}=X system, {2,3}=Y system ----
__global__ __launch_bounds__(256, 1) void row_kernel(
    const float* __restrict__ s, const float* __restrict__ eIF,
    const float* __restrict__ xm, const float* __restrict__ ym,
    const float* __restrict__ sum_x, const float* __restrict__ sum_y,
    const float* __restrict__ lamuda, const float* __restrict__ init_freqs,
    const int* __restrict__ mode_mask, const float* __restrict__ alpha_p,
    const float* __restrict__ beta_p, const float* __restrict__ var_p,
    const float* __restrict__ fs_p, const int* __restrict__ iter_p,
    const float* __restrict__ fe_w1, const float* __restrict__ fe_b1,
    const float* __restrict__ fe_w2, const float* __restrict__ fe_b2,
    const float* __restrict__ pr_w1, const float* __restrict__ pr_b1,
    const float* __restrict__ pr_w2, const float* __restrict__ pr_b2,
    const float* __restrict__ pr_w3, const float* __restrict__ pr_b3,
    const float* __restrict__ iter_w_p, double* __restrict__ hdr,
    float* __restrict__ out_eIF, float* __restrict__ out_xm,
    float* __restrict__ out_ym, float* __restrict__ cx_w,
    float* __restrict__ cy_w, float* __restrict__ out_scal) {
  __shared__ double sh_avg[Bq];
  __shared__ double sh_h1[Bq][32];
  __shared__ double sh_z[Bq][18];
  __shared__ double sh_z1[Bq][64];
  __shared__ double sh_z2[Bq][32];
  __shared__ double sh_res[Bq][2];
  __shared__ double sh_hdr[4];
  __shared__ double sh_sc[8];
  __shared__ float sh_part[4][4];
  __shared__ float sh_rb[4][2];
  __shared__ float sh_xs[Nq], sh_ys[Nq];

  const int tid = threadIdx.x;
  const int wv = tid >> 6, lane = tid & 63;
  const int pair = wv >> 1, half = wv & 1;
  const int row = blockIdx.x, b = row >> 2;
  const int bb = b * Nq, base = row * Nq;
  const int seg0 = half * 1024;

  // ---- hyperparameter MLP (redundant per block, f64 deterministic) ----
  double alpha = (double)alpha_p[0], beta = (double)beta_p[0];
  double iterv = (double)iter_p[0];
  if (tid < Bq) {
    double avg = 0.0;
#pragma unroll
    for (int k = 0; k < Kq; ++k) avg += (double)init_freqs[tid * Kq + k];
    sh_avg[tid] = avg * (1.0 / Kq);
  }
  __syncthreads();
  {
    int b2 = tid >> 5, j = tid & 31;
    double v = (double)fe_w1[j] * sh_avg[b2] + (double)fe_b1[j];
    sh_h1[b2][j] = v > 0.0 ? v : 0.0;
  }
  __syncthreads();
  if (tid < 128) {
    int b2 = tid >> 4, j = tid & 15;
    double acc = (double)fe_b2[j];
    for (int i = 0; i < 32; ++i) acc += (double)fe_w2[j * 32 + i] * sh_h1[b2][i];
    sh_z[b2][j] = acc > 0.0 ? acc : 0.0;
  }
  if (tid >= 128 && tid < 128 + Bq) {
    sh_z[tid - 128][16] = alpha;
    sh_z[tid - 128][17] = beta;
  }
  __syncthreads();
  for (int n = tid; n < 512; n += 256) {
    int b2 = n >> 6, j = n & 63;
    double acc = (double)pr_b1[j];
    for (int i = 0; i < 18; ++i) acc += (double)pr_w1[j * 18 + i] * sh_z[b2][i];
    sh_z1[b2][j] = acc > 0.0 ? acc : 0.0;
  }
  __syncthreads();
  {
    int b2 = tid >> 5, j = tid & 31;
    double acc = (double)pr_b2[j];
    for (int i = 0; i < 64; ++i) acc += (double)pr_w2[j * 64 + i] * sh_z1[b2][i];
    sh_z2[b2][j] = acc > 0.0 ? acc : 0.0;
  }
  __syncthreads();
  if (tid < 16) {
    int b2 = tid >> 1, c = tid & 1;
    double acc = (double)pr_b3[c];
    for (int i = 0; i < 32; ++i) acc += (double)pr_w3[c * 32 + i] * sh_z2[b2][i];
    double fac = 1.0 / (1.0 + exp(-(double)iter_w_p[0] * iterv));
    sh_res[b2][c] = tanh(acc) * fac * 0.1;
  }
  __syncthreads();
  if (tid == 0) {
    double r0 = 0.0, r1 = 0.0;
    for (int q = 0; q < Bq; ++q) { r0 += sh_res[q][0]; r1 += sh_res[q][1]; }
    double na = fmin(fmax(alpha + r0 * alpha * (1.0 / Bq), 1e-6), 0.01);
    double nb2 = fmin(fmax(beta + r1 * beta * (1.0 / Bq), 1e-6), 0.1);
    double betathr = fmin(pow(10.0, iterv / 36.0 - 10.0), nb2);
    sh_hdr[0] = na;
    sh_hdr[1] = 2.0 / na;       // coefA
    sh_hdr[2] = 2.0 / betathr;  // coefS
    sh_hdr[3] = 1.0 / na;       // inv_alpha
    hdr[0] = na;                // identical across blocks
    hdr[4] = 1.0 / na;
    out_scal[0] = (float)na;
    out_scal[1] = (float)nb2;
  }
  __syncthreads();
  const float coefA = (float)sh_hdr[1];
  const float coefS = (float)sh_hdr[2];
  const double inva = sh_hdr[3];

  // ---- u-norm partial (own segment, f64) + eIF segment scan ----
  double tv[NE];
  {
    double n0 = 0.0;
#pragma unroll
    for (int e = 0; e < NE; ++e) {
      int gi = bb + seg0 + lane * NE + e;
      tv[e] = (double)s[gi] - (double)sum_x[gi] - (double)sum_y[gi] -
              (double)lamuda[gi] * inva;
      n0 += tv[e] * tv[e];
    }
    double np = wave_sum_d(n0);
    if (pair == 0 && lane == 0) sh_sc[4 + half] = np;
  }
  const double dx = 1.0 / (double)fs_p[0];
  const double c0 = PI_D * dx;
  double ev[NE], pl[NE];
#pragma unroll
  for (int e = 0; e < NE; ++e) ev[e] = (double)eIF[base + seg0 + lane * NE + e];
  pl[0] = ev[0];
#pragma unroll
  for (int e = 1; e < NE; ++e) pl[e] = pl[e - 1] + ev[e];
  double offs_w = lane_excl_prefix_d(pl[NE - 1], lane);
  {
    double segT = __shfl(offs_w + pl[NE - 1], 63, 64);
    if (pair == 0 && lane == 0) sh_sc[half] = segT;
    if (pair == 0 && half == 0 && lane == 0) sh_sc[2] = ev[0];
  }
  __syncthreads();
  double offs = offs_w + (half ? sh_sc[0] : 0.0);
  double y0 = sh_sc[2];
  {
    double nsq = sh_sc[4] + sh_sc[5];
    double nn = sqrt(nsq);
    double ee = sqrt((double)Nq * (double)var_p[0]);
    double scale = (nn > ee) ? ee / fmax(nn, 1e-30) : 1.0;
    double oms = 1.0 - scale;
#pragma unroll
    for (int e = 0; e < NE; ++e) tv[e] *= oms;
  }

  // ---- trig + per-pair system build ----
  float dd[NE], r[NE], x[NE];
#pragma unroll
  for (int e = 0; e < NE; ++e) {
    int i = seg0 + lane * NE + e;
    double ph = c0 * (2.0 * (offs + pl[e]) - ev[e] - y0);  // 2*pi*cumtrapz
    float sn, cs;
    fast_sincos_ph(ph, &sn, &cs);
    float xmv = xm[base + i], ymv = ym[base + i];
    double resid = tv[e] + (double)xmv * (double)cs + (double)ymv * (double)sn;
    if (pair == 0) {
      dd[e] = cs * cs + 1e-6f;
      r[e] = (float)((double)cs * resid);
      x[e] = xmv;
    } else {
      dd[e] = sn * sn + 1e-6f;
      r[e] = (float)((double)sn * resid);
      x[e] = ymv;
    }
  }
  // x0 boundary halos (direct global loads)
  {
    const float* src = (pair == 0) ? (xm + base) : (ym + base);
    float hxL0 = 0.f, hxL1 = 0.f, hxR0 = 0.f, hxR1 = 0.f;
    if (half == 0) { hxR0 = src[1024]; hxR1 = src[1025]; }
    else { hxL0 = src[1022]; hxL1 = src[1023]; }
    cg_wave2<false>(coefA, dd, r, x, hxL0, hxL1, hxR0, hxR1, lane, half, wv,
                    sh_part, sh_rb);
  }

  // publish xs/ys (full row in LDS, global-indexed)
  {
    float* dst = (pair == 0) ? sh_xs : sh_ys;
#pragma unroll
    for (int e = 0; e < NE; ++e) dst[seg0 + lane * NE + e] = x[e];
  }
  __syncthreads();

  // ---- deltaIF for own segment (reads full-row LDS) ----
  {
    float invdx = (float)fs_p[0], inv2dx = 0.5f * invdx;
#pragma unroll
    for (int e = 0; e < NE; ++e) {
      int i = seg0 + lane * NE + e;
      float xc = sh_xs[i], yc = sh_ys[i];
      float xb, yb;
      if (i == 0) {
        xb = (sh_xs[1] - sh_xs[0]) * invdx;
        yb = (sh_ys[1] - sh_ys[0]) * invdx;
      } else if (i == Nq - 1) {
        xb = (sh_xs[Nq - 1] - sh_xs[Nq - 2]) * invdx;
        yb = (sh_ys[Nq - 1] - sh_ys[Nq - 2]) * invdx;
      } else {
        xb = (sh_xs[i + 1] - sh_xs[i - 1]) * inv2dx;
        yb = (sh_ys[i + 1] - sh_ys[i - 1]) * inv2dx;
      }
      float denom = xc * xc + yc * yc + 1e-12f;
      r[e] = (xc * yb - yc * xb) / (denom * (float)TWO_PI_D);
      x[e] = 0.0f;
    }
  }
  __syncthreads();  // all sh_xs/sh_ys reads done before sh_part/sh_rb reuse

  // ---- smooth CG (both pairs solve the identical system) ----
  cg_wave2<true>(coefS, nullptr, r, x, 0.f, 0.f, 0.f, 0.f, lane, half, wv,
                 sh_part, sh_rb);

  // ---- epilogue: outputs + new-phase contributions (own segment) ----
  bool active = mode_mask[row] != 0;
  double eifn[NE];
#pragma unroll
  for (int e = 0; e < NE; ++e) {
    int i = seg0 + lane * NE + e;
    double eifv = (double)eIF[base + i];
    eifn[e] = active ? (eifv - 0.5 * (double)x[e]) : eifv;
  }
  if (pair == 0) {
#pragma unroll
    for (int e = 0; e < NE; ++e) {
      int i = seg0 + lane * NE + e;
      out_eIF[base + i] = (float)eifn[e];
      out_xm[base + i] = active ? sh_xs[i] : xm[base + i];
    }
  } else {
#pragma unroll
    for (int e = 0; e < NE; ++e) {
      int i = seg0 + lane * NE + e;
      out_ym[base + i] = active ? sh_ys[i] : ym[base + i];
    }
  }
  pl[0] = eifn[0];
#pragma unroll
  for (int e = 1; e < NE; ++e) pl[e] = pl[e - 1] + eifn[e];
  offs_w = lane_excl_prefix_d(pl[NE - 1], lane);
  {
    double segT = __shfl(offs_w + pl[NE - 1], 63, 64);
    if (pair == 0 && half == 0 && lane == 0) sh_sc[6] = segT;
    if (pair == 0 && half == 0 && lane == 0) sh_sc[3] = eifn[0];
  }
  __syncthreads();
  {
    double offs2 = offs_w + (half ? sh_sc[6] : 0.0);
    double y02 = sh_sc[3];
#pragma unroll
    for (int e = 0; e < NE; ++e) {
      int i = seg0 + lane * NE + e;
      double ph = c0 * (2.0 * (offs2 + pl[e]) - eifn[e] - y02);
      float sn, cs;
      fast_sincos_ph(ph, &sn, &cs);
      if (pair == 0)
        cx_w[base + i] = active ? sh_xs[i] * cs : 0.0f;
      else
        cy_w[base + i] = active ? sh_ys[i] * sn : 0.0f;
    }
  }
}

// ---------------- final: bsx/bsy sums + u + new lamuda ----------------
__global__ __launch_bounds__(256) void final_kernel(
    const float* __restrict__ s, const float* __restrict__ sum_x,
    const float* __restrict__ sum_y, const float* __restrict__ lamuda,
    const float* __restrict__ var_p, const double* __restrict__ hdr,
    const float* __restrict__ cx_w, const float* __restrict__ cy_w,
    float* __restrict__ out_bsx, float* __restrict__ out_bsy,
    float* __restrict__ out_lam) {
  __shared__ double sh_red[4];
  __shared__ double sh_scale;
  int b = blockIdx.x;
  int bb = b * Nq;
  int tid = threadIdx.x;
  double na = hdr[0], inva = hdr[4];
  double t[8];
  double loc = 0.0;
#pragma unroll
  for (int e = 0; e < 8; ++e) {
    int gi = bb + tid + e * 256;
    t[e] = (double)s[gi] - (double)sum_x[gi] - (double)sum_y[gi] -
           (double)lamuda[gi] * inva;
    loc += t[e] * t[e];
  }
  double nsq = blk_reduce(loc, sh_red);
  if (tid == 0) {
    double n = sqrt(nsq);
    double ee = sqrt((double)Nq * (double)var_p[0]);
    sh_scale = (n > ee) ? ee / fmax(n, 1e-30) : 1.0;
  }
  __syncthreads();
  double scale = sh_scale;
#pragma unroll
  for (int e = 0; e < 8; ++e) {
    int i = tid + e * 256;
    int gi = bb + i;
    double bx = 0.0, by = 0.0;
#pragma unroll
    for (int k = 0; k < Kq; ++k) {
      bx += (double)cx_w[(b * Kq + k) * Nq + i];
      by += (double)cy_w[(b * Kq + k) * Nq + i];
    }
    double u = t[e] * scale;
    double nl = (double)lamuda[gi] + na * (u + bx + by - (double)s[gi]);
    out_bsx[gi] = (float)bx;
    out_bsy[gi] = (float)by;
    out_lam[gi] = (float)nl;
  }
}

// ---------------- launcher ----------------
extern "C" void kernel_launch(void* const* d_in, const int* in_sizes, int n_in,
                              void* d_out, int out_size, void* d_ws, size_t ws_size,
                              hipStream_t stream) {
  (void)in_sizes; (void)n_in; (void)out_size; (void)ws_size;
  const float* s = (const float*)d_in[0];
  const float* eIF = (const float*)d_in[1];
  const float* xm = (const float*)d_in[2];
  const float* ym = (const float*)d_in[3];
  const float* sum_x = (const float*)d_in[4];
  const float* sum_y = (const float*)d_in[5];
  const float* lamuda = (const float*)d_in[6];
  const float* init_freqs = (const float*)d_in[7];
  const int* mode_mask = (const int*)d_in[8];
  const float* alpha = (const float*)d_in[9];
  const float* beta = (const float*)d_in[10];
  const float* var = (const float*)d_in[11];
  const float* fs = (const float*)d_in[12];
  const int* iteration = (const int*)d_in[13];
  const float* fe_w1 = (const float*)d_in[14];
  const float* fe_b1 = (const float*)d_in[15];
  const float* fe_w2 = (const float*)d_in[16];
  const float* fe_b2 = (const float*)d_in[17];
  const float* pr_w1 = (const float*)d_in[18];
  const float* pr_b1 = (const float*)d_in[19];
  const float* pr_w2 = (const float*)d_in[20];
  const float* pr_b2 = (const float*)d_in[21];
  const float* pr_w3 = (const float*)d_in[22];
  const float* pr_b3 = (const float*)d_in[23];
  const float* iter_weight = (const float*)d_in[24];

  float* out = (float*)d_out;
  const int BN = Bq * Nq;      // 16384
  const int BKN = BKq * Nq;    // 65536
  float* out_eIF = out;
  float* out_xm = out + BKN;
  float* out_ym = out + 2 * BKN;
  float* out_bsx = out + 3 * BKN;
  float* out_bsy = out + 3 * BKN + BN;
  float* out_lam = out + 3 * BKN + 2 * BN;
  float* out_scal = out + 3 * BKN + 3 * BN;  // [new_alpha, new_beta]

  double* W = (double*)d_ws;
  double* hdr = W;                   // 16 doubles
  float* F = (float*)(W + 16);
  float* cx_w = F;                   // BKN floats
  float* cy_w = F + BKN;             // BKN floats

  row_kernel<<<BKq, 256, 0, stream>>>(
      s, eIF, xm, ym, sum_x, sum_y, lamuda, init_freqs, mode_mask, alpha, beta,
      var, fs, iteration, fe_w1, fe_b1, fe_w2, fe_b2, pr_w1, pr_b1, pr_w2,
      pr_b2, pr_w3, pr_b3, iter_weight, hdr, out_eIF, out_xm, out_ym, cx_w,
      cy_w, out_scal);
  final_kernel<<<Bq, 256, 0, stream>>>(s, sum_x, sum_y, lamuda, var, hdr, cx_w,
                                       cy_w, out_bsx, out_bsy, out_lam);
}